// Round 9
// baseline (1059.013 us; speedup 1.0000x reference)
//
#include <hip/hip_runtime.h>
#include <math.h>

#define GRID_SZ 128
#define NC 196
#define NC4 49                // NC/4 float4 per row
#define G2 (GRID_SZ*GRID_SZ)  // 16384
#define UPTS 64               // sorted pairs per wave in gather (divides N)
#define NBITS 18              // meta packing: low 18 bits = n, high 14 = cell

// ---------------- wave-aggregated atomic helpers ----------------

__device__ __forceinline__ void agg_hist(int bin, bool valid, int lane,
                                         unsigned int* __restrict__ hist) {
    unsigned long long todo = __ballot(valid);
    while (todo) {
        const int leader = __ffsll((long long)todo) - 1;
        const int lb = __shfl(bin, leader);
        const unsigned long long match = __ballot(valid && bin == lb);
        if (lane == leader) atomicAdd(&hist[lb], (unsigned)__popcll(match));
        todo &= ~match;
    }
}

__device__ __forceinline__ void agg_scatter(int bin, unsigned pk, bool valid, int lane,
                                            unsigned int* __restrict__ cursor,
                                            unsigned int* __restrict__ meta) {
    unsigned long long todo = __ballot(valid);
    while (todo) {
        const int leader = __ffsll((long long)todo) - 1;
        const int lb = __shfl(bin, leader);
        const unsigned long long match = __ballot(valid && bin == lb);
        unsigned base = 0;
        if (lane == leader) base = atomicAdd(&cursor[lb], (unsigned)__popcll(match));
        base = __shfl((int)base, leader);
        if (valid && bin == lb) {
            const unsigned rank = (unsigned)__popcll(match & ((1ull << lane) - 1ull));
            meta[base + rank] = pk;
        }
        todo &= ~match;
    }
}

// ---------------- K1: per-point cell ids + histogram (3 planes/thread) ----------------

__global__ __launch_bounds__(256) void cellid_hist_kernel(
    const float* __restrict__ gs, const float* __restrict__ sb,
    unsigned short* __restrict__ cellid, unsigned int* __restrict__ hist,
    int B, int N) {
    const long long P = (long long)B * N;
    const long long p = (long long)blockIdx.x * blockDim.x + threadIdx.x;
    const bool valid = (p < P);
    const int lane = threadIdx.x & 63;

    int bin0 = -1, bin1 = -1, bin2 = -1;
    if (valid) {
        const int b = (int)(p / N);
        const int n = (int)(p - (long long)b * N);
        const float4 head = *(const float4*)(gs + (size_t)p * NC);

        const float i0 = 1.0f / (sb[1] - sb[0]);
        const float i1 = 1.0f / (sb[3] - sb[2]);
        const float i2 = 1.0f / (sb[5] - sb[4]);
        int gx = (int)((head.x - sb[0]) * i0 * 127.0f);
        int gy = (int)((head.y - sb[2]) * i1 * 127.0f);
        int gz = (int)((head.z - sb[4]) * i2 * 127.0f);
        gx = min(127, max(0, gx));
        gy = min(127, max(0, gy));
        gz = min(127, max(0, gz));

        const int c0 = gx * GRID_SZ + gy;
        const int c1 = gx * GRID_SZ + gz;
        const int c2 = gy * GRID_SZ + gz;
        cellid[(size_t)(b * 3 + 0) * N + n] = (unsigned short)c0;
        cellid[(size_t)(b * 3 + 1) * N + n] = (unsigned short)c1;
        cellid[(size_t)(b * 3 + 2) * N + n] = (unsigned short)c2;
        bin0 = (b * 3 + 0) * G2 + c0;
        bin1 = (b * 3 + 1) * G2 + c1;
        bin2 = (b * 3 + 2) * G2 + c2;
    }
    agg_hist(bin0, valid, lane, hist);
    agg_hist(bin1, valid, lane, hist);
    agg_hist(bin2, valid, lane, hist);
}

// ---------------- K2: 3-phase exclusive scans ----------------

__global__ __launch_bounds__(256) void scanA_kernel(const unsigned int* __restrict__ hist,
                                                    unsigned int* __restrict__ cursor,
                                                    unsigned int* __restrict__ partials,
                                                    int NB) {
    __shared__ unsigned int s[256];
    const int t = threadIdx.x;
    const int g = blockIdx.x * 256 + t;
    const unsigned v = (g < NB) ? hist[g] : 0u;
    s[t] = v;
    __syncthreads();
    for (int off = 1; off < 256; off <<= 1) {
        const unsigned u = (t >= off) ? s[t - off] : 0u;
        __syncthreads();
        s[t] += u;
        __syncthreads();
    }
    if (g < NB) cursor[g] = s[t] - v;      // exclusive
    if (t == 255) partials[blockIdx.x] = s[255];
}

__global__ __launch_bounds__(256) void scanA_occ_kernel(const unsigned int* __restrict__ hist,
                                                        int* __restrict__ cid,
                                                        unsigned int* __restrict__ partials,
                                                        int NB) {
    __shared__ unsigned int s[256];
    const int t = threadIdx.x;
    const int g = blockIdx.x * 256 + t;
    const unsigned v = (g < NB && hist[g] > 0u) ? 1u : 0u;
    s[t] = v;
    __syncthreads();
    for (int off = 1; off < 256; off <<= 1) {
        const unsigned u = (t >= off) ? s[t - off] : 0u;
        __syncthreads();
        s[t] += u;
        __syncthreads();
    }
    if (g < NB) cid[g] = (int)(s[t] - v);  // exclusive
    if (t == 255) partials[blockIdx.x] = s[255];
}

__global__ __launch_bounds__(1024) void scanB_kernel(unsigned int* __restrict__ partials,
                                                     int np, unsigned int* __restrict__ total) {
    __shared__ unsigned int s[1024];
    const int t = threadIdx.x;
    const unsigned v = (t < np) ? partials[t] : 0u;
    s[t] = v;
    __syncthreads();
    for (int off = 1; off < 1024; off <<= 1) {
        const unsigned u = (t >= off) ? s[t - off] : 0u;
        __syncthreads();
        s[t] += u;
        __syncthreads();
    }
    if (t < np) partials[t] = s[t] - v;    // exclusive
    if (total != nullptr && t == np - 1) *total = s[t];  // inclusive sum
}

__global__ __launch_bounds__(256) void scanC_kernel(unsigned int* __restrict__ arr,
                                                    const unsigned int* __restrict__ partials,
                                                    int NB) {
    const int g = blockIdx.x * 256 + threadIdx.x;
    if (g < NB) arr[g] += partials[blockIdx.x];
}

__global__ __launch_bounds__(256) void scanC_int_kernel(int* __restrict__ arr,
                                                        const unsigned int* __restrict__ partials,
                                                        int NB) {
    const int g = blockIdx.x * 256 + threadIdx.x;
    if (g < NB) arr[g] += (int)partials[blockIdx.x];
}

// ---------------- zero kernels ----------------

__global__ void zero_kernel(float4* __restrict__ p, long long n4) {
    long long i = (long long)blockIdx.x * blockDim.x + threadIdx.x;
    long long stride = (long long)gridDim.x * blockDim.x;
    const float4 z = make_float4(0.f, 0.f, 0.f, 0.f);
    for (; i < n4; i += stride) p[i] = z;
}

__global__ void zero_dyn_kernel(float4* __restrict__ nwc4, float* __restrict__ dnc,
                                const unsigned int* __restrict__ total) {
    const unsigned T = *total;
    const long long n4 = (long long)T * NC4;
    long long i = (long long)blockIdx.x * blockDim.x + threadIdx.x;
    const long long stride = (long long)gridDim.x * blockDim.x;
    const float4 z = make_float4(0.f, 0.f, 0.f, 0.f);
    for (long long k = i; k < n4; k += stride) nwc4[k] = z;
    for (long long k = i; k < (long long)T; k += stride) dnc[k] = 0.f;
}

// ---------------- K3: per-point scatter (3 planes/thread, packed meta) ----------------

__global__ __launch_bounds__(256) void scatter_kernel(
    const unsigned short* __restrict__ cellid, unsigned int* __restrict__ cursor,
    unsigned int* __restrict__ meta, int B, int N) {
    const long long P = (long long)B * N;
    const long long p = (long long)blockIdx.x * blockDim.x + threadIdx.x;
    const bool valid = (p < P);
    const int lane = threadIdx.x & 63;

    unsigned pk0 = 0, pk1 = 0, pk2 = 0;
    int bin0 = -1, bin1 = -1, bin2 = -1;
    if (valid) {
        const int b = (int)(p / N);
        const int n = (int)(p - (long long)b * N);
        const unsigned c0 = cellid[(size_t)(b * 3 + 0) * N + n];
        const unsigned c1 = cellid[(size_t)(b * 3 + 1) * N + n];
        const unsigned c2 = cellid[(size_t)(b * 3 + 2) * N + n];
        bin0 = (b * 3 + 0) * G2 + (int)c0;
        bin1 = (b * 3 + 1) * G2 + (int)c1;
        bin2 = (b * 3 + 2) * G2 + (int)c2;
        pk0 = (c0 << NBITS) | (unsigned)n;
        pk1 = (c1 << NBITS) | (unsigned)n;
        pk2 = (c2 << NBITS) | (unsigned)n;
    }
    agg_scatter(bin0, pk0, valid, lane, cursor, meta);
    agg_scatter(bin1, pk1, valid, lane, cursor, meta);
    agg_scatter(bin2, pk2, valid, lane, cursor, meta);
}

// ---------------- K4: depth-4 batched-issue pipelined gather-reduce ----------------

__device__ __forceinline__ void flush_bin_c(int cell, const int* __restrict__ cidSec,
                                            const float4& acc, float den,
                                            float* __restrict__ nwc, float* __restrict__ dnc,
                                            int lane) {
    if (cell < 0) return;
    const int cc = cidSec[cell];
    if (lane < NC4) {
        float* base = nwc + (size_t)cc * NC + 4 * lane;
        unsafeAtomicAdd(base + 0, acc.x);
        unsafeAtomicAdd(base + 1, acc.y);
        unsafeAtomicAdd(base + 2, acc.z);
        unsafeAtomicAdd(base + 3, acc.w);
    } else if (lane == NC4) {
        unsafeAtomicAdd(dnc + cc, den);
    }
}

__global__ __launch_bounds__(256) void gather_kernel(
    const float* __restrict__ gs, const float* __restrict__ sb,
    const unsigned int* __restrict__ meta, const int* __restrict__ cid,
    float* __restrict__ nwc, float* __restrict__ dnc,
    int N, long long Q) {
    const int lane = threadIdx.x & 63;
    const long long wave = (long long)blockIdx.x * 4 + (threadIdx.x >> 6);
    const long long i0 = wave * (long long)UPTS;
    if (i0 >= Q) return;
    // N % UPTS == 0 -> every chunk is exactly UPTS, within one (batch,plane) section

    const int sec = (int)(i0 / N);            // wave-constant
    const int b = sec / 3;                    // wave-constant
    const float4* brows = (const float4*)gs + (size_t)b * N * NC4;
    const int* cidSec = cid + sec * G2;

    const float lo0 = sb[0], hi0 = sb[1];
    const float lo1 = sb[2], hi1 = sb[3];
    const float lo2 = sb[4], hi2 = sb[5];
    const float s0 = 2.0f / (hi0 - lo0);
    const float s1 = 2.0f / (hi1 - lo1);
    const float s2 = 2.0f / (hi2 - lo2);

    const float4 f40 = make_float4(0.f, 0.f, 0.f, 0.f);
    const unsigned int* mt = meta + i0;
    const bool ld = (lane < NC4);
    const unsigned NMASK = (1u << NBITS) - 1u;

    // meta pipeline: A = current group j, B = next group j+4
    unsigned mA0 = mt[0], mA1 = mt[1], mA2 = mt[2], mA3 = mt[3];
    unsigned mB0 = mt[4], mB1 = mt[5], mB2 = mt[6], mB3 = mt[7];

    // rows + heads for group 0
    const float4* p0 = brows + (size_t)(mA0 & NMASK) * NC4;
    const float4* p1 = brows + (size_t)(mA1 & NMASK) * NC4;
    const float4* p2 = brows + (size_t)(mA2 & NMASK) * NC4;
    const float4* p3 = brows + (size_t)(mA3 & NMASK) * NC4;
    float4 v0 = ld ? p0[lane] : f40; float4 h0 = p0[0];
    float4 v1 = ld ? p1[lane] : f40; float4 h1 = p1[0];
    float4 v2 = ld ? p2[lane] : f40; float4 h2 = p2[0];
    float4 v3 = ld ? p3[lane] : f40; float4 h3 = p3[0];

    int curCell = -1;
    float4 acc = f40;
    float accD = 0.f;

#define CONSUME(V, H, CELL)                                                 \
    {                                                                       \
        const float cnx = (H.x - lo0) * s0 - 1.0f;                          \
        const float cny = (H.y - lo1) * s1 - 1.0f;                          \
        const float cnz = (H.z - lo2) * s2 - 1.0f;                          \
        const float alpha = 1.0f / (1.0f + __expf(-H.w));                   \
        float4 vv = V;                                                      \
        if (lane == 0) { vv.x = cnx; vv.y = cny; vv.z = cnz; }              \
        const float4 av = make_float4(vv.x * alpha, vv.y * alpha,           \
                                      vv.z * alpha, vv.w * alpha);          \
        if ((CELL) != curCell) {                                            \
            flush_bin_c(curCell, cidSec, acc, accD, nwc, dnc, lane);        \
            curCell = (CELL); acc = av; accD = alpha;                       \
        } else {                                                            \
            acc.x += av.x; acc.y += av.y; acc.z += av.z; acc.w += av.w;     \
            accD += alpha;                                                  \
        }                                                                   \
    }

    for (int j = 0; j < UPTS; j += 4) {
        // 1) batch-issue row+head loads for group j+4 (unconditional)
        const float4* q0 = brows + (size_t)(mB0 & NMASK) * NC4;
        const float4* q1 = brows + (size_t)(mB1 & NMASK) * NC4;
        const float4* q2 = brows + (size_t)(mB2 & NMASK) * NC4;
        const float4* q3 = brows + (size_t)(mB3 & NMASK) * NC4;
        float4 t0 = ld ? q0[lane] : f40; float4 g0 = q0[0];
        float4 t1 = ld ? q1[lane] : f40; float4 g1 = q1[0];
        float4 t2 = ld ? q2[lane] : f40; float4 g2 = q2[0];
        float4 t3 = ld ? q3[lane] : f40; float4 g3 = q3[0];

        // 2) prefetch meta for group j+8 (clamped -> no conditionals)
        const int m0 = (j + 8  < UPTS) ? j + 8  : UPTS - 1;
        const int m1 = (j + 9  < UPTS) ? j + 9  : UPTS - 1;
        const int m2 = (j + 10 < UPTS) ? j + 10 : UPTS - 1;
        const int m3 = (j + 11 < UPTS) ? j + 11 : UPTS - 1;
        const unsigned mT0 = mt[m0], mT1 = mt[m1], mT2 = mt[m2], mT3 = mt[m3];

        // 3) consume current group (registers loaded last iteration)
        CONSUME(v0, h0, (int)(mA0 >> NBITS));
        CONSUME(v1, h1, (int)(mA1 >> NBITS));
        CONSUME(v2, h2, (int)(mA2 >> NBITS));
        CONSUME(v3, h3, (int)(mA3 >> NBITS));

        // 4) rotate pipeline
        v0 = t0; v1 = t1; v2 = t2; v3 = t3;
        h0 = g0; h1 = g1; h2 = g2; h3 = g3;
        mA0 = mB0; mA1 = mB1; mA2 = mB2; mA3 = mB3;
        mB0 = mT0; mB1 = mT1; mB2 = mT2; mB3 = mT3;
    }
    flush_bin_c(curCell, cidSec, acc, accD, nwc, dnc, lane);
#undef CONSUME
}

// ---------------- K5: transpose + normalize from compact ----------------

#define TCELLS 64
__global__ __launch_bounds__(256) void xpose_c_kernel(
    const float* __restrict__ nwc, const float* __restrict__ dnc,
    const int* __restrict__ cid, const unsigned int* __restrict__ hist,
    float* __restrict__ out) {
    __shared__ float tile[TCELLS][197];   // pad: conflict-free column reads
    __shared__ float dinv[TCELLS];
    __shared__ int scid[TCELLS];
    const int t = threadIdx.x;
    const int pg = blockIdx.x >> 8;              // plane index (256 tiles/plane)
    const int c0 = (blockIdx.x & 255) * TCELLS;

    if (t < TCELLS) {
        const int bin = pg * G2 + c0 + t;
        const int cc = (hist[bin] > 0u) ? cid[bin] : -1;
        scid[t] = cc;
        dinv[t] = (cc >= 0) ? 1.0f / fmaxf(dnc[cc], 1e-6f) : 0.0f;
    }
    __syncthreads();

    const float4 f40 = make_float4(0.f, 0.f, 0.f, 0.f);
    for (int i = t; i < TCELLS * NC4; i += 256) {
        const int cell = i / NC4;
        const int cp = i - cell * NC4;
        const int cc = scid[cell];
        float4 v = (cc >= 0) ? ((const float4*)(nwc + (size_t)cc * NC))[cp] : f40;
        float* dst = &tile[cell][cp * 4];
        dst[0] = v.x; dst[1] = v.y; dst[2] = v.z; dst[3] = v.w;
    }
    __syncthreads();

    float* obase = out + (size_t)pg * NC * G2 + c0;
    for (int i = t; i < TCELLS * NC; i += 256) {
        const int c = i >> 6;
        const int cell = i & 63;
        obase[(size_t)c * G2 + cell] = tile[cell][c] * dinv[cell];
    }
}

// ---------------- fallback (direct channel-major, R1-style) ----------------

struct Slot { int tag; float den; float4 acc; };

__device__ __forceinline__ void slot_flush(const Slot& s, float* __restrict__ out,
                                           float* __restrict__ den,
                                           size_t outPlaneBase, int denPlaneBase, int lane) {
    if (s.tag < 0) return;
    if (lane < NC4) {
        size_t base = outPlaneBase + (size_t)(4 * lane) * G2 + (size_t)s.tag;
        unsafeAtomicAdd(out + base,                s.acc.x);
        unsafeAtomicAdd(out + base + (size_t)G2,   s.acc.y);
        unsafeAtomicAdd(out + base + (size_t)2*G2, s.acc.z);
        unsafeAtomicAdd(out + base + (size_t)3*G2, s.acc.w);
    }
    if (lane == 0) unsafeAtomicAdd(den + denPlaneBase + s.tag, s.den);
}

__device__ __forceinline__ void plane_acc(Slot& a, Slot& b, int cell, float alpha,
                                          const float4& av,
                                          float* __restrict__ out, float* __restrict__ den,
                                          size_t outPlaneBase, int denPlaneBase, int lane) {
    if (cell == a.tag) {
        a.acc.x += av.x; a.acc.y += av.y; a.acc.z += av.z; a.acc.w += av.w; a.den += alpha;
    } else if (cell == b.tag) {
        b.acc.x += av.x; b.acc.y += av.y; b.acc.z += av.z; b.acc.w += av.w; b.den += alpha;
    } else {
        if (b.den > a.den) { Slot t = a; a = b; b = t; }
        slot_flush(b, out, den, outPlaneBase, denPlaneBase, lane);
        b.tag = cell; b.den = alpha; b.acc = av;
    }
}

__global__ __launch_bounds__(256) void splat_kernel(
    const float* __restrict__ gs, const float* __restrict__ sb,
    float* __restrict__ out, float* __restrict__ den, int B, int N, int ppw) {
    const int lane = threadIdx.x & 63;
    const long long wave = (long long)blockIdx.x * (blockDim.x >> 6) + (threadIdx.x >> 6);
    const long long totalPts = (long long)B * N;
    long long start = wave * ppw;
    if (start >= totalPts) return;
    long long end = start + ppw;
    if (end > totalPts) end = totalPts;
    const int bb = (int)(start / N);

    const float lo0 = sb[0], hi0 = sb[1];
    const float lo1 = sb[2], hi1 = sb[3];
    const float lo2 = sb[4], hi2 = sb[5];
    const float s0 = 2.0f / (hi0 - lo0);
    const float s1 = 2.0f / (hi1 - lo1);
    const float s2 = 2.0f / (hi2 - lo2);

    const size_t ob0 = ((size_t)(bb * 3 + 0) * NC) * G2;
    const size_t ob1 = ((size_t)(bb * 3 + 1) * NC) * G2;
    const size_t ob2 = ((size_t)(bb * 3 + 2) * NC) * G2;
    const int db0 = (bb * 3 + 0) * G2;
    const int db1 = (bb * 3 + 1) * G2;
    const int db2 = (bb * 3 + 2) * G2;

    const float4 f40 = make_float4(0.f, 0.f, 0.f, 0.f);
    Slot a0{-1,0.f,f40}, t0{-1,0.f,f40}, a1{-1,0.f,f40}, t1{-1,0.f,f40},
         a2{-1,0.f,f40}, t2{-1,0.f,f40};

    const float4* rows = (const float4*)gs;
    const float4* r0 = rows + (size_t)start * NC4;
    float4 v = (lane < NC4) ? r0[lane] : f40;
    float4 h = r0[0];

    for (long long i = start; i < end; ++i) {
        float4 vn = f40, hn = f40;
        if (i + 1 < end) {
            const float4* rn = rows + (size_t)(i + 1) * NC4;
            vn = (lane < NC4) ? rn[lane] : f40;
            hn = rn[0];
        }
        const float cnx = (h.x - lo0) * s0 - 1.0f;
        const float cny = (h.y - lo1) * s1 - 1.0f;
        const float cnz = (h.z - lo2) * s2 - 1.0f;
        int gx = (int)((cnx * 0.5f + 0.5f) * 127.0f);
        int gy = (int)((cny * 0.5f + 0.5f) * 127.0f);
        int gz = (int)((cnz * 0.5f + 0.5f) * 127.0f);
        gx = min(127, max(0, gx)); gy = min(127, max(0, gy)); gz = min(127, max(0, gz));
        const int cxy = __builtin_amdgcn_readfirstlane(gx * GRID_SZ + gy);
        const int cxz = __builtin_amdgcn_readfirstlane(gx * GRID_SZ + gz);
        const int cyz = __builtin_amdgcn_readfirstlane(gy * GRID_SZ + gz);
        const float alpha = 1.0f / (1.0f + __expf(-h.w));
        float4 vv = v;
        if (lane == 0) { vv.x = cnx; vv.y = cny; vv.z = cnz; }
        const float4 av = make_float4(vv.x*alpha, vv.y*alpha, vv.z*alpha, vv.w*alpha);
        plane_acc(a0, t0, cxy, alpha, av, out, den, ob0, db0, lane);
        plane_acc(a1, t1, cxz, alpha, av, out, den, ob1, db1, lane);
        plane_acc(a2, t2, cyz, alpha, av, out, den, ob2, db2, lane);
        v = vn; h = hn;
    }
    slot_flush(a0, out, den, ob0, db0, lane);
    slot_flush(t0, out, den, ob0, db0, lane);
    slot_flush(a1, out, den, ob1, db1, lane);
    slot_flush(t1, out, den, ob1, db1, lane);
    slot_flush(a2, out, den, ob2, db2, lane);
    slot_flush(t2, out, den, ob2, db2, lane);
}

__global__ void normalize_kernel(float* __restrict__ out, const float* __restrict__ den,
                                 int total4) {
    int idx = blockIdx.x * blockDim.x + threadIdx.x;
    const int stride = gridDim.x * blockDim.x;
    for (; idx < total4; idx += stride) {
        float4 v = ((float4*)out)[idx];
        const int e = idx * 4;
        const int cell = e & (G2 - 1);
        const int bp = e / (NC * G2);
        const float4 d = *(const float4*)(den + bp * G2 + cell);
        v.x /= fmaxf(d.x, 1e-6f);
        v.y /= fmaxf(d.y, 1e-6f);
        v.z /= fmaxf(d.z, 1e-6f);
        v.w /= fmaxf(d.w, 1e-6f);
        ((float4*)out)[idx] = v;
    }
}

// ---------------- launch ----------------

extern "C" void kernel_launch(void* const* d_in, const int* in_sizes, int n_in,
                              void* d_out, int out_size, void* d_ws, size_t ws_size,
                              hipStream_t stream) {
    const float* gs = (const float*)d_in[0];
    const float* sb = (const float*)d_in[1];
    float* out = (float*)d_out;

    const int B = out_size / (3 * NC * G2);                            // 4
    const int N = (int)((long long)in_sizes[0] / ((long long)B * NC)); // 131072
    const long long P = (long long)B * N;                              // 524288
    const long long Q = P * 3;                                         // 1.57M
    const int NB = B * 3 * G2;                                         // 196608

    const size_t nwF = (size_t)NB * NC;          // compact worst case = full
    const size_t dnF = (size_t)NB;
    size_t off = 0;
    const size_t o_nw = off;     off += nwF * 4;
    const size_t o_dn = off;     off += dnF * 4;
    const size_t o_hist = off;   off += (size_t)NB * 4;
    const size_t o_cur = off;    off += (size_t)NB * 4;
    const size_t o_cid = off;    off += (size_t)NB * 4;
    const size_t o_part = off;   off += 1024 * 4;
    const size_t o_part2 = off;  off += 1024 * 4;
    const size_t o_total = off;  off += 256;
    const size_t o_cell = off;   off += ((size_t)Q * 2 + 255) & ~255ull;
    const size_t o_meta = off;   off += (size_t)Q * 4;
    const size_t need = off;

    const int nPart = (NB + 255) / 256;          // 768

    if (ws_size >= need && nPart <= 1024 && (N % UPTS) == 0 && N <= (1 << NBITS)) {
        char* ws = (char*)d_ws;
        float* nwc = (float*)(ws + o_nw);
        float* dnc = (float*)(ws + o_dn);
        unsigned int* hist = (unsigned int*)(ws + o_hist);
        unsigned int* cur = (unsigned int*)(ws + o_cur);
        int* cid = (int*)(ws + o_cid);
        unsigned int* part = (unsigned int*)(ws + o_part);
        unsigned int* part2 = (unsigned int*)(ws + o_part2);
        unsigned int* total = (unsigned int*)(ws + o_total);
        unsigned short* cellid = (unsigned short*)(ws + o_cell);
        unsigned int* meta = (unsigned int*)(ws + o_meta);

        zero_kernel<<<256, 256, 0, stream>>>((float4*)hist, (long long)NB / 4);

        const int pBlocks = (int)((P + 255) / 256);                    // 2048
        cellid_hist_kernel<<<pBlocks, 256, 0, stream>>>(gs, sb, cellid, hist, B, N);

        scanA_kernel<<<nPart, 256, 0, stream>>>(hist, cur, part, NB);
        scanA_occ_kernel<<<nPart, 256, 0, stream>>>(hist, cid, part2, NB);
        scanB_kernel<<<1, 1024, 0, stream>>>(part, nPart, nullptr);
        scanB_kernel<<<1, 1024, 0, stream>>>(part2, nPart, total);
        scanC_kernel<<<nPart, 256, 0, stream>>>(cur, part, NB);
        scanC_int_kernel<<<nPart, 256, 0, stream>>>(cid, part2, NB);

        zero_dyn_kernel<<<2048, 256, 0, stream>>>((float4*)nwc, dnc, total);

        scatter_kernel<<<pBlocks, 256, 0, stream>>>(cellid, cur, meta, B, N);

        const long long gWaves = Q / UPTS;                             // 24576
        const int gBlocks = (int)((gWaves + 3) / 4);                   // 6144
        gather_kernel<<<gBlocks, 256, 0, stream>>>(gs, sb, meta, cid, nwc, dnc, N, Q);

        const int xblocks = B * 3 * (G2 / TCELLS);                     // 3072
        xpose_c_kernel<<<xblocks, 256, 0, stream>>>(nwc, dnc, cid, hist, out);
    } else {
        float* den = (float*)d_ws;
        const long long out4 = (long long)out_size / 4;
        const long long den4 = (long long)dnF / 4;
        const int ppw = 64;
        const long long waves = ((long long)B * N) / ppw;
        const int blocks = (int)((waves + 3) / 4);
        zero_kernel<<<2048, 256, 0, stream>>>((float4*)out, out4);
        zero_kernel<<<256, 256, 0, stream>>>((float4*)den, den4);
        splat_kernel<<<blocks, 256, 0, stream>>>(gs, sb, out, den, B, N, ppw);
        normalize_kernel<<<4096, 256, 0, stream>>>(out, den, (int)out4);
    }
}

// Round 10
// 607.528 us; speedup vs baseline: 1.7432x; 1.7432x over previous
//
#include <hip/hip_runtime.h>
#include <math.h>

#define GRID_SZ 128
#define NC 196
#define NC4 49                // NC/4 float4 per row
#define G2 (GRID_SZ*GRID_SZ)  // 16384
#define UPTS 128              // sorted points per wave in gather (divides N)
#define KB 21                 // spatial key bits: gx<<14 | gy<<7 | gz

// ---------------- wave-aggregated atomic helpers ----------------

__device__ __forceinline__ void agg_hist(int bin, bool valid, int lane,
                                         unsigned int* __restrict__ hist) {
    unsigned long long todo = __ballot(valid);
    while (todo) {
        const int leader = __ffsll((long long)todo) - 1;
        const int lb = __shfl(bin, leader);
        const unsigned long long match = __ballot(valid && bin == lb);
        if (lane == leader) atomicAdd(&hist[lb], (unsigned)__popcll(match));
        todo &= ~match;
    }
}

// ---------------- K1: per-point triple key + histograms ----------------

__global__ __launch_bounds__(256) void key_hist_kernel(
    const float* __restrict__ gs, const float* __restrict__ sb,
    unsigned int* __restrict__ keys, unsigned int* __restrict__ hist21,
    unsigned int* __restrict__ hist, int B, int N) {
    const long long P = (long long)B * N;
    const long long p = (long long)blockIdx.x * blockDim.x + threadIdx.x;
    const bool valid = (p < P);
    const int lane = threadIdx.x & 63;

    int key = -1, bin0 = -1, bin1 = -1, bin2 = -1;
    if (valid) {
        const int b = (int)(p / N);
        const float4 head = *(const float4*)(gs + (size_t)p * NC);

        const float i0 = 1.0f / (sb[1] - sb[0]);
        const float i1 = 1.0f / (sb[3] - sb[2]);
        const float i2 = 1.0f / (sb[5] - sb[4]);
        int gx = (int)((head.x - sb[0]) * i0 * 127.0f);
        int gy = (int)((head.y - sb[2]) * i1 * 127.0f);
        int gz = (int)((head.z - sb[4]) * i2 * 127.0f);
        gx = min(127, max(0, gx));
        gy = min(127, max(0, gy));
        gz = min(127, max(0, gz));

        key = (b << KB) | (gx << 14) | (gy << 7) | gz;
        keys[p] = (unsigned)key;
        bin0 = (b * 3 + 0) * G2 + (gx * GRID_SZ + gy);
        bin1 = (b * 3 + 1) * G2 + (gx * GRID_SZ + gz);
        bin2 = (b * 3 + 2) * G2 + (gy * GRID_SZ + gz);
    }
    agg_hist(key, valid, lane, hist21);
    agg_hist(bin0, valid, lane, hist);
    agg_hist(bin1, valid, lane, hist);
    agg_hist(bin2, valid, lane, hist);
}

// ---------------- K2: scan kernels ----------------

__global__ __launch_bounds__(256) void scanA_kernel(const unsigned int* __restrict__ hist,
                                                    unsigned int* __restrict__ cursor,
                                                    unsigned int* __restrict__ partials,
                                                    int NBn) {
    __shared__ unsigned int s[256];
    const int t = threadIdx.x;
    const int g = blockIdx.x * 256 + t;
    const unsigned v = (g < NBn) ? hist[g] : 0u;
    s[t] = v;
    __syncthreads();
    for (int off = 1; off < 256; off <<= 1) {
        const unsigned u = (t >= off) ? s[t - off] : 0u;
        __syncthreads();
        s[t] += u;
        __syncthreads();
    }
    if (g < NBn) cursor[g] = s[t] - v;     // exclusive
    if (t == 255) partials[blockIdx.x] = s[255];
}

__global__ __launch_bounds__(256) void scanA_occ_kernel(const unsigned int* __restrict__ hist,
                                                        int* __restrict__ cid,
                                                        unsigned int* __restrict__ partials,
                                                        int NBn) {
    __shared__ unsigned int s[256];
    const int t = threadIdx.x;
    const int g = blockIdx.x * 256 + t;
    const unsigned v = (g < NBn && hist[g] > 0u) ? 1u : 0u;
    s[t] = v;
    __syncthreads();
    for (int off = 1; off < 256; off <<= 1) {
        const unsigned u = (t >= off) ? s[t - off] : 0u;
        __syncthreads();
        s[t] += u;
        __syncthreads();
    }
    if (g < NBn) cid[g] = (int)(s[t] - v); // exclusive
    if (t == 255) partials[blockIdx.x] = s[255];
}

__global__ __launch_bounds__(1024) void scanB_kernel(unsigned int* __restrict__ partials,
                                                     int np, unsigned int* __restrict__ total) {
    __shared__ unsigned int s[1024];
    const int t = threadIdx.x;
    const unsigned v = (t < np) ? partials[t] : 0u;
    s[t] = v;
    __syncthreads();
    for (int off = 1; off < 1024; off <<= 1) {
        const unsigned u = (t >= off) ? s[t - off] : 0u;
        __syncthreads();
        s[t] += u;
        __syncthreads();
    }
    if (t < np) partials[t] = s[t] - v;    // exclusive
    if (total != nullptr && t == np - 1) *total = s[t];
}

__global__ __launch_bounds__(256) void scanC_kernel(unsigned int* __restrict__ arr,
                                                    const unsigned int* __restrict__ partials,
                                                    int NBn) {
    const int g = blockIdx.x * 256 + threadIdx.x;
    if (g < NBn) arr[g] += partials[blockIdx.x];
}

__global__ __launch_bounds__(256) void scanC_int_kernel(int* __restrict__ arr,
                                                        const unsigned int* __restrict__ partials,
                                                        int NBn) {
    const int g = blockIdx.x * 256 + threadIdx.x;
    if (g < NBn) arr[g] += (int)partials[blockIdx.x];
}

// ---------------- zero kernels ----------------

__global__ void zero_kernel(float4* __restrict__ p, long long n4) {
    long long i = (long long)blockIdx.x * blockDim.x + threadIdx.x;
    long long stride = (long long)gridDim.x * blockDim.x;
    const float4 z = make_float4(0.f, 0.f, 0.f, 0.f);
    for (; i < n4; i += stride) p[i] = z;
}

__global__ void zero_dyn_kernel(float4* __restrict__ nwc4, float* __restrict__ dnc,
                                const unsigned int* __restrict__ total) {
    const unsigned T = *total;
    const long long n4 = (long long)T * NC4;
    long long i = (long long)blockIdx.x * blockDim.x + threadIdx.x;
    const long long stride = (long long)gridDim.x * blockDim.x;
    const float4 z = make_float4(0.f, 0.f, 0.f, 0.f);
    for (long long k = i; k < n4; k += stride) nwc4[k] = z;
    for (long long k = i; k < (long long)T; k += stride) dnc[k] = 0.f;
}

// ---------------- K3: scatter into triple-sorted order ----------------

__global__ __launch_bounds__(256) void scatter3_kernel(
    const unsigned int* __restrict__ keys, unsigned int* __restrict__ cur21,
    unsigned int* __restrict__ sn, unsigned int* __restrict__ skey,
    int B, int N) {
    const long long P = (long long)B * N;
    const long long p = (long long)blockIdx.x * blockDim.x + threadIdx.x;
    const bool valid = (p < P);
    const int lane = threadIdx.x & 63;

    int key = -1, n = 0;
    if (valid) {
        const int b = (int)(p / N);
        n = (int)(p - (long long)b * N);
        key = (int)keys[p];
    }

    unsigned long long todo = __ballot(valid);
    while (todo) {
        const int leader = __ffsll((long long)todo) - 1;
        const int lk = __shfl(key, leader);
        const unsigned long long match = __ballot(valid && key == lk);
        unsigned base = 0;
        if (lane == leader) base = atomicAdd(&cur21[lk], (unsigned)__popcll(match));
        base = __shfl((int)base, leader);
        if (valid && key == lk) {
            const unsigned rank = (unsigned)__popcll(match & ((1ull << lane) - 1ull));
            sn[base + rank] = (unsigned)n;
            skey[base + rank] = (unsigned)key;
        }
        todo &= ~match;
    }
}

// ---------------- K4: triple-sorted gather-reduce (one row read per point) --------

__device__ __forceinline__ void flush3(int key, const int* __restrict__ cid,
                                       const float4& acc, float accD,
                                       float* __restrict__ nwc, float* __restrict__ dnc,
                                       int lane) {
    if (key < 0) return;
    const int b = key >> KB;
    const int gx = (key >> 14) & 127;
    const int gy = (key >> 7) & 127;
    const int gz = key & 127;
    const int cc0 = cid[(b * 3 + 0) * G2 + gx * GRID_SZ + gy];
    const int cc1 = cid[(b * 3 + 1) * G2 + gx * GRID_SZ + gz];
    const int cc2 = cid[(b * 3 + 2) * G2 + gy * GRID_SZ + gz];
    if (lane < NC4) {
        float* b0 = nwc + (size_t)cc0 * NC + 4 * lane;
        float* b1 = nwc + (size_t)cc1 * NC + 4 * lane;
        float* b2 = nwc + (size_t)cc2 * NC + 4 * lane;
        unsafeAtomicAdd(b0 + 0, acc.x); unsafeAtomicAdd(b0 + 1, acc.y);
        unsafeAtomicAdd(b0 + 2, acc.z); unsafeAtomicAdd(b0 + 3, acc.w);
        unsafeAtomicAdd(b1 + 0, acc.x); unsafeAtomicAdd(b1 + 1, acc.y);
        unsafeAtomicAdd(b1 + 2, acc.z); unsafeAtomicAdd(b1 + 3, acc.w);
        unsafeAtomicAdd(b2 + 0, acc.x); unsafeAtomicAdd(b2 + 1, acc.y);
        unsafeAtomicAdd(b2 + 2, acc.z); unsafeAtomicAdd(b2 + 3, acc.w);
    } else if (lane == NC4) {
        unsafeAtomicAdd(dnc + cc0, accD);
        unsafeAtomicAdd(dnc + cc1, accD);
        unsafeAtomicAdd(dnc + cc2, accD);
    }
}

__global__ __launch_bounds__(256) void gather3_kernel(
    const float* __restrict__ gs, const float* __restrict__ sb,
    const unsigned int* __restrict__ sn, const unsigned int* __restrict__ skey,
    const int* __restrict__ cid,
    float* __restrict__ nwc, float* __restrict__ dnc,
    int N, long long P) {
    const int lane = threadIdx.x & 63;
    const long long wave = (long long)blockIdx.x * 4 + (threadIdx.x >> 6);
    const long long i0 = wave * (long long)UPTS;
    if (i0 >= P) return;
    // N % UPTS == 0 -> chunk stays within one batch (keys sorted, batch-major)

    const unsigned int* psn = sn + i0;
    const unsigned int* psk = skey + i0;

    const unsigned k0 = psk[0];
    const int b = (int)(k0 >> KB);                    // wave-constant
    const float4* brows = (const float4*)gs + (size_t)b * N * NC4;

    const float lo0 = sb[0], hi0 = sb[1];
    const float lo1 = sb[2], hi1 = sb[3];
    const float lo2 = sb[4], hi2 = sb[5];
    const float s0 = 2.0f / (hi0 - lo0);
    const float s1 = 2.0f / (hi1 - lo1);
    const float s2 = 2.0f / (hi2 - lo2);

    const float4 f40 = make_float4(0.f, 0.f, 0.f, 0.f);
    const bool ld = (lane < NC4);

    // depth-1 row pipeline, depth-2 meta pipeline
    unsigned nA = psn[0];      unsigned kA = k0;
    unsigned nB_ = psn[1];     unsigned kB_ = psk[1];

    const float4* pA = brows + (size_t)nA * NC4;
    float4 v = ld ? pA[lane] : f40;
    float4 h = pA[0];

    int curKey = -1;
    float4 acc = f40;
    float accD = 0.f;

    for (int j = 0; j < UPTS; ++j) {
        // issue next row (clamped tail -> redundant reload of last row, harmless)
        const float4* pN = brows + (size_t)nB_ * NC4;
        float4 vn = ld ? pN[lane] : f40;
        float4 hn = pN[0];

        // prefetch meta j+2
        const int m = (j + 2 < UPTS) ? j + 2 : UPTS - 1;
        const unsigned nT = psn[m];
        const unsigned kT = psk[m];

        // consume point j
        const float cnx = (h.x - lo0) * s0 - 1.0f;
        const float cny = (h.y - lo1) * s1 - 1.0f;
        const float cnz = (h.z - lo2) * s2 - 1.0f;
        const float alpha = 1.0f / (1.0f + __expf(-h.w));
        float4 vv = v;
        if (lane == 0) { vv.x = cnx; vv.y = cny; vv.z = cnz; }
        const float4 av = make_float4(vv.x * alpha, vv.y * alpha,
                                      vv.z * alpha, vv.w * alpha);
        if ((int)kA != curKey) {
            flush3(curKey, cid, acc, accD, nwc, dnc, lane);
            curKey = (int)kA; acc = av; accD = alpha;
        } else {
            acc.x += av.x; acc.y += av.y; acc.z += av.z; acc.w += av.w;
            accD += alpha;
        }

        v = vn; h = hn;
        nA = nB_; kA = kB_;
        nB_ = nT; kB_ = kT;
    }
    flush3(curKey, cid, acc, accD, nwc, dnc, lane);
}

// ---------------- K5: transpose + normalize from compact ----------------

#define TCELLS 64
__global__ __launch_bounds__(256) void xpose_c_kernel(
    const float* __restrict__ nwc, const float* __restrict__ dnc,
    const int* __restrict__ cid, const unsigned int* __restrict__ hist,
    float* __restrict__ out) {
    __shared__ float tile[TCELLS][197];   // pad: conflict-free column reads
    __shared__ float dinv[TCELLS];
    __shared__ int scid[TCELLS];
    const int t = threadIdx.x;
    const int pg = blockIdx.x >> 8;              // plane index (256 tiles/plane)
    const int c0 = (blockIdx.x & 255) * TCELLS;

    if (t < TCELLS) {
        const int bin = pg * G2 + c0 + t;
        const int cc = (hist[bin] > 0u) ? cid[bin] : -1;
        scid[t] = cc;
        dinv[t] = (cc >= 0) ? 1.0f / fmaxf(dnc[cc], 1e-6f) : 0.0f;
    }
    __syncthreads();

    const float4 f40 = make_float4(0.f, 0.f, 0.f, 0.f);
    for (int i = t; i < TCELLS * NC4; i += 256) {
        const int cell = i / NC4;
        const int cp = i - cell * NC4;
        const int cc = scid[cell];
        float4 v = (cc >= 0) ? ((const float4*)(nwc + (size_t)cc * NC))[cp] : f40;
        float* dst = &tile[cell][cp * 4];
        dst[0] = v.x; dst[1] = v.y; dst[2] = v.z; dst[3] = v.w;
    }
    __syncthreads();

    float* obase = out + (size_t)pg * NC * G2 + c0;
    for (int i = t; i < TCELLS * NC; i += 256) {
        const int c = i >> 6;
        const int cell = i & 63;
        obase[(size_t)c * G2 + cell] = tile[cell][c] * dinv[cell];
    }
}

// ---------------- fallback (direct channel-major, R1-style) ----------------

struct Slot { int tag; float den; float4 acc; };

__device__ __forceinline__ void slot_flush(const Slot& s, float* __restrict__ out,
                                           float* __restrict__ den,
                                           size_t outPlaneBase, int denPlaneBase, int lane) {
    if (s.tag < 0) return;
    if (lane < NC4) {
        size_t base = outPlaneBase + (size_t)(4 * lane) * G2 + (size_t)s.tag;
        unsafeAtomicAdd(out + base,                s.acc.x);
        unsafeAtomicAdd(out + base + (size_t)G2,   s.acc.y);
        unsafeAtomicAdd(out + base + (size_t)2*G2, s.acc.z);
        unsafeAtomicAdd(out + base + (size_t)3*G2, s.acc.w);
    }
    if (lane == 0) unsafeAtomicAdd(den + denPlaneBase + s.tag, s.den);
}

__device__ __forceinline__ void plane_acc(Slot& a, Slot& b, int cell, float alpha,
                                          const float4& av,
                                          float* __restrict__ out, float* __restrict__ den,
                                          size_t outPlaneBase, int denPlaneBase, int lane) {
    if (cell == a.tag) {
        a.acc.x += av.x; a.acc.y += av.y; a.acc.z += av.z; a.acc.w += av.w; a.den += alpha;
    } else if (cell == b.tag) {
        b.acc.x += av.x; b.acc.y += av.y; b.acc.z += av.z; b.acc.w += av.w; b.den += alpha;
    } else {
        if (b.den > a.den) { Slot t = a; a = b; b = t; }
        slot_flush(b, out, den, outPlaneBase, denPlaneBase, lane);
        b.tag = cell; b.den = alpha; b.acc = av;
    }
}

__global__ __launch_bounds__(256) void splat_kernel(
    const float* __restrict__ gs, const float* __restrict__ sb,
    float* __restrict__ out, float* __restrict__ den, int B, int N, int ppw) {
    const int lane = threadIdx.x & 63;
    const long long wave = (long long)blockIdx.x * (blockDim.x >> 6) + (threadIdx.x >> 6);
    const long long totalPts = (long long)B * N;
    long long start = wave * ppw;
    if (start >= totalPts) return;
    long long end = start + ppw;
    if (end > totalPts) end = totalPts;
    const int bb = (int)(start / N);

    const float lo0 = sb[0], hi0 = sb[1];
    const float lo1 = sb[2], hi1 = sb[3];
    const float lo2 = sb[4], hi2 = sb[5];
    const float s0 = 2.0f / (hi0 - lo0);
    const float s1 = 2.0f / (hi1 - lo1);
    const float s2 = 2.0f / (hi2 - lo2);

    const size_t ob0 = ((size_t)(bb * 3 + 0) * NC) * G2;
    const size_t ob1 = ((size_t)(bb * 3 + 1) * NC) * G2;
    const size_t ob2 = ((size_t)(bb * 3 + 2) * NC) * G2;
    const int db0 = (bb * 3 + 0) * G2;
    const int db1 = (bb * 3 + 1) * G2;
    const int db2 = (bb * 3 + 2) * G2;

    const float4 f40 = make_float4(0.f, 0.f, 0.f, 0.f);
    Slot a0{-1,0.f,f40}, t0{-1,0.f,f40}, a1{-1,0.f,f40}, t1{-1,0.f,f40},
         a2{-1,0.f,f40}, t2{-1,0.f,f40};

    const float4* rows = (const float4*)gs;
    const float4* r0 = rows + (size_t)start * NC4;
    float4 v = (lane < NC4) ? r0[lane] : f40;
    float4 h = r0[0];

    for (long long i = start; i < end; ++i) {
        float4 vn = f40, hn = f40;
        if (i + 1 < end) {
            const float4* rn = rows + (size_t)(i + 1) * NC4;
            vn = (lane < NC4) ? rn[lane] : f40;
            hn = rn[0];
        }
        const float cnx = (h.x - lo0) * s0 - 1.0f;
        const float cny = (h.y - lo1) * s1 - 1.0f;
        const float cnz = (h.z - lo2) * s2 - 1.0f;
        int gx = (int)((cnx * 0.5f + 0.5f) * 127.0f);
        int gy = (int)((cny * 0.5f + 0.5f) * 127.0f);
        int gz = (int)((cnz * 0.5f + 0.5f) * 127.0f);
        gx = min(127, max(0, gx)); gy = min(127, max(0, gy)); gz = min(127, max(0, gz));
        const int cxy = __builtin_amdgcn_readfirstlane(gx * GRID_SZ + gy);
        const int cxz = __builtin_amdgcn_readfirstlane(gx * GRID_SZ + gz);
        const int cyz = __builtin_amdgcn_readfirstlane(gy * GRID_SZ + gz);
        const float alpha = 1.0f / (1.0f + __expf(-h.w));
        float4 vv = v;
        if (lane == 0) { vv.x = cnx; vv.y = cny; vv.z = cnz; }
        const float4 av = make_float4(vv.x*alpha, vv.y*alpha, vv.z*alpha, vv.w*alpha);
        plane_acc(a0, t0, cxy, alpha, av, out, den, ob0, db0, lane);
        plane_acc(a1, t1, cxz, alpha, av, out, den, ob1, db1, lane);
        plane_acc(a2, t2, cyz, alpha, av, out, den, ob2, db2, lane);
        v = vn; h = hn;
    }
    slot_flush(a0, out, den, ob0, db0, lane);
    slot_flush(t0, out, den, ob0, db0, lane);
    slot_flush(a1, out, den, ob1, db1, lane);
    slot_flush(t1, out, den, ob1, db1, lane);
    slot_flush(a2, out, den, ob2, db2, lane);
    slot_flush(t2, out, den, ob2, db2, lane);
}

__global__ void normalize_kernel(float* __restrict__ out, const float* __restrict__ den,
                                 int total4) {
    int idx = blockIdx.x * blockDim.x + threadIdx.x;
    const int stride = gridDim.x * blockDim.x;
    for (; idx < total4; idx += stride) {
        float4 v = ((float4*)out)[idx];
        const int e = idx * 4;
        const int cell = e & (G2 - 1);
        const int bp = e / (NC * G2);
        const float4 d = *(const float4*)(den + bp * G2 + cell);
        v.x /= fmaxf(d.x, 1e-6f);
        v.y /= fmaxf(d.y, 1e-6f);
        v.z /= fmaxf(d.z, 1e-6f);
        v.w /= fmaxf(d.w, 1e-6f);
        ((float4*)out)[idx] = v;
    }
}

// ---------------- launch ----------------

extern "C" void kernel_launch(void* const* d_in, const int* in_sizes, int n_in,
                              void* d_out, int out_size, void* d_ws, size_t ws_size,
                              hipStream_t stream) {
    const float* gs = (const float*)d_in[0];
    const float* sb = (const float*)d_in[1];
    float* out = (float*)d_out;

    const int B = out_size / (3 * NC * G2);                            // 4
    const int N = (int)((long long)in_sizes[0] / ((long long)B * NC)); // 131072
    const long long P = (long long)B * N;                              // 524288
    const int NB = B * 3 * G2;                                         // 196608
    const long long NB21 = (long long)B << KB;                         // 8.4M

    const size_t nwF = (size_t)NB * NC;
    const size_t dnF = (size_t)NB;
    size_t off = 0;
    const size_t o_nw = off;      off += nwF * 4;
    const size_t o_dn = off;      off += dnF * 4;
    const size_t o_hist21 = off;  off += (size_t)NB21 * 4;   // contiguous with hist
    const size_t o_hist = off;    off += (size_t)NB * 4;
    const size_t o_cur21 = off;   off += (size_t)NB21 * 4;
    const size_t o_cid = off;     off += (size_t)NB * 4;
    const size_t o_part1 = off;   off += ((size_t)NB21 / 256 + 256) * 4;
    const size_t o_part1x = off;  off += ((size_t)NB21 / 256 + 256) * 4;
    const size_t o_part2 = off;   off += 1024 * 4;
    const size_t o_partO = off;   off += 1024 * 4;
    const size_t o_total = off;   off += 256;
    const size_t o_keys = off;    off += (size_t)P * 4;
    const size_t o_sn = off;      off += (size_t)P * 4;
    const size_t o_skey = off;    off += (size_t)P * 4;
    const size_t need = off;

    const int blocks21 = (int)(NB21 / 256);      // 32768 (NB21 multiple of 256)
    const int nPart1 = (blocks21 + 255) / 256;   // 128
    const int nPartO = (NB + 255) / 256;         // 768

    if (ws_size >= need && B <= 64 && nPart1 <= 1024 && nPartO <= 1024 &&
        (N % UPTS) == 0 && (NB21 % 256) == 0) {
        char* ws = (char*)d_ws;
        float* nwc = (float*)(ws + o_nw);
        float* dnc = (float*)(ws + o_dn);
        unsigned int* hist21 = (unsigned int*)(ws + o_hist21);
        unsigned int* hist = (unsigned int*)(ws + o_hist);
        unsigned int* cur21 = (unsigned int*)(ws + o_cur21);
        int* cid = (int*)(ws + o_cid);
        unsigned int* part1 = (unsigned int*)(ws + o_part1);
        unsigned int* part1x = (unsigned int*)(ws + o_part1x);
        unsigned int* part2 = (unsigned int*)(ws + o_part2);
        unsigned int* partO = (unsigned int*)(ws + o_partO);
        unsigned int* total = (unsigned int*)(ws + o_total);
        unsigned int* keys = (unsigned int*)(ws + o_keys);
        unsigned int* sn = (unsigned int*)(ws + o_sn);
        unsigned int* skey = (unsigned int*)(ws + o_skey);

        // zero hist21 + hist (contiguous)
        zero_kernel<<<2048, 256, 0, stream>>>((float4*)hist21,
                                              (NB21 + (long long)NB) / 4);

        const int pBlocks = (int)((P + 255) / 256);                    // 2048
        key_hist_kernel<<<pBlocks, 256, 0, stream>>>(gs, sb, keys, hist21, hist, B, N);

        // 3-level scan of hist21 -> cur21
        scanA_kernel<<<blocks21, 256, 0, stream>>>(hist21, cur21, part1, (int)NB21);
        scanA_kernel<<<nPart1, 256, 0, stream>>>(part1, part1x, part2, blocks21);
        scanB_kernel<<<1, 1024, 0, stream>>>(part2, nPart1, nullptr);
        scanC_kernel<<<nPart1, 256, 0, stream>>>(part1x, part2, blocks21);
        scanC_kernel<<<blocks21, 256, 0, stream>>>(cur21, part1x, (int)NB21);

        // per-plane compaction scan
        scanA_occ_kernel<<<nPartO, 256, 0, stream>>>(hist, cid, partO, NB);
        scanB_kernel<<<1, 1024, 0, stream>>>(partO, nPartO, total);
        scanC_int_kernel<<<nPartO, 256, 0, stream>>>(cid, partO, NB);

        zero_dyn_kernel<<<2048, 256, 0, stream>>>((float4*)nwc, dnc, total);

        scatter3_kernel<<<pBlocks, 256, 0, stream>>>(keys, cur21, sn, skey, B, N);

        const long long gWaves = P / UPTS;                             // 4096
        const int gBlocks = (int)((gWaves + 3) / 4);                   // 1024
        gather3_kernel<<<gBlocks, 256, 0, stream>>>(gs, sb, sn, skey, cid,
                                                    nwc, dnc, N, P);

        const int xblocks = B * 3 * (G2 / TCELLS);                     // 3072
        xpose_c_kernel<<<xblocks, 256, 0, stream>>>(nwc, dnc, cid, hist, out);
    } else {
        float* den = (float*)d_ws;
        const long long out4 = (long long)out_size / 4;
        const long long den4 = (long long)dnF / 4;
        const int ppw = 64;
        const long long waves = ((long long)B * N) / ppw;
        const int blocks = (int)((waves + 3) / 4);
        zero_kernel<<<2048, 256, 0, stream>>>((float4*)out, out4);
        zero_kernel<<<256, 256, 0, stream>>>((float4*)den, den4);
        splat_kernel<<<blocks, 256, 0, stream>>>(gs, sb, out, den, B, N, ppw);
        normalize_kernel<<<4096, 256, 0, stream>>>(out, den, (int)out4);
    }
}